// Round 7
// baseline (410.240 us; speedup 1.0000x reference)
//
#include <hip/hip_runtime.h>
#include <cstdint>
#include <cstddef>

typedef __bf16 bf16;
typedef __bf16 bf16x8 __attribute__((ext_vector_type(8)));
typedef float f32x4 __attribute__((ext_vector_type(4)));

#define BDIM 4
#define TDIM 2048
#define DDIM 2048
#define HDIM 8
#define DHD 256
#define MTOT 8192
#define NCHUNK 64
#define LCHUNK 32

// async 16B global->LDS; LDS dest = wave-uniform base + lane*16
__device__ __forceinline__ void stage16(const bf16* g, bf16* l) {
  __builtin_amdgcn_global_load_lds(
      (const __attribute__((address_space(1))) void*)g,
      (__attribute__((address_space(3))) void*)l, 16, 0, 0);
}

// intrinsic barrier (no implicit drain); BARE asm waitcnt (no "memory" clobber
// -> no compiler-inserted vmcnt(0)/lgkmcnt(0) drain; round-6 lesson).
#define BARX() __builtin_amdgcn_s_barrier()
#define SCHB() __builtin_amdgcn_sched_barrier(0)
#define WAITVM(N) asm volatile("s_waitcnt vmcnt(" #N ")")

__device__ __forceinline__ float sigmoid_f(float x) {
  return __fdividef(1.f, 1.f + __expf(-x));
}
__device__ __forceinline__ float gelu_tanh(float v) {
  float u = 0.7978845608028654f * (v + 0.044715f * v * v * v);
  u = fminf(fmaxf(u, -15.f), 15.f);
  float t = __expf(2.f * u);                       // tanh(u) = (t-1)/(t+1)
  return 0.5f * v * (1.f + __fdividef(t - 1.f, t + 1.f));
}
__device__ __forceinline__ float softplus_f(float x) {
  return __logf(1.f + __expf(x));                  // x in [-1.2, 0.4] here
}

// ---------------------------------------------------------------------------
// fp32 -> bf16 bulk convert, 8 elem/thread (count must be /2048)
// ---------------------------------------------------------------------------
__global__ __launch_bounds__(256) void f2b(const float* __restrict__ src,
                                           bf16* __restrict__ dst) {
  size_t i = ((size_t)blockIdx.x * 256 + threadIdx.x) * 8;
  const float4 a = *(const float4*)(src + i);
  const float4 b = *(const float4*)(src + i + 4);
  bf16x8 r;
  r[0] = (bf16)a.x; r[1] = (bf16)a.y; r[2] = (bf16)a.z; r[3] = (bf16)a.w;
  r[4] = (bf16)b.x; r[5] = (bf16)b.y; r[6] = (bf16)b.z; r[7] = (bf16)b.w;
  *(bf16x8*)(dst + i) = r;
}

// ---------------------------------------------------------------------------
// C[m,n] = epi(sum_k A[m,k]*B[n,k] + bias[n]); bf16 operands, fp32 accum.
// 256x256 tile, BK=64, 8 waves (2M x 4N). FOUR DISTINCT __shared__ objects
// (sA0/sA1/sB0/sB1, 32 KiB each) so ds_read vs global_load_lds LDS-writes are
// provably non-aliasing; K-loop x2-unrolled so buffer choice is compile-time.
// XOR-8 16B-slot swizzle (0 conflicts measured).
//
// Per K-tile, 4 phases; reads issued ONE PHASE AHEAD of consumption; stages
// issued BEFORE reads; gate -> stage -> reads -> MFMA -> barrier:
//   ph1: VM(4); stg HB1(t+1)->oth ; rd b1(t)      ; MFMA(0,0) aq0xb0 ; BAR
//   ph2:        stg HA1(t+1)->oth ; rd aq1(t)     ; MFMA(0,1) aq0xb1 ; BAR
//   ph3:        stg HB0(t+2)->self;               ; MFMA(1,0) aq1xb0 ; BAR
//   ph4: VM(6); stg HA0(t+2)->self; rd aq0,b0(t+1); MFMA(1,1) aq1xb1 ; BAR
// vmcnt ledger (per wave, 2 loads/stage, in-order): steady outstanding
// [HB1(t),HA1(t),HB0(t+1),HA0(t+1)] at ph1 -> VM(4) retires HB1/HA1(t);
// at ph4 (10 out) VM(6) retires HB0/HA0(t+1). Never drains in-loop; staged
// data gated >= 1 full K-tile (~4000cy) after issue >> HBM latency.
// Stage safety: every overwritten region's reads were consumed by an MFMA
// >= 2 barriers earlier (checked per phase). Tail stages clamp to NT-1
// (garbage into dead slots, never read); WAITVM(0) after loop drains.
// XCD-chunked block swizzle. Requires M,N%256==0, K%128==0, nwg%8==0.
// ---------------------------------------------------------------------------
template <typename TO, int EPI>
__global__ __launch_bounds__(512, 2) void gemm256(
    const bf16* __restrict__ A, const bf16* __restrict__ Bm,
    const float* __restrict__ bias, TO* __restrict__ C,
    int K, int lda, int ldb, int ldc) {
  const int gx = gridDim.x, gy = gridDim.y;
  const int nwg = gx * gy;
  const int did = blockIdx.x + gx * blockIdx.y;
  const int cpx = nwg >> 3;                       // chunk per XCD
  const int lid = (did & 7) * cpx + (did >> 3);
  const int n0 = (lid % gx) * 256;
  const int m0 = (lid / gx) * 256;

  __shared__ bf16 sA0[256 * 64];    // 32 KiB each; distinct objects ->
  __shared__ bf16 sA1[256 * 64];    // compiler proves stage-write vs ds_read
  __shared__ bf16 sB0[256 * 64];    // independence (no conservative waits)
  __shared__ bf16 sB1[256 * 64];
  const int tid = threadIdx.x;
  const int lane = tid & 63;
  const int wid = tid >> 6;         // 0..7
  const int wr = wid >> 2;          // M-half of tile (128 rows)
  const int wc = wid & 3;           // N-quarter (64 cols)
  const int quad = lane >> 4;
  const int l15 = lane & 15;

  // staging: thread covers row (c*64 + tid>>3), swizzled 16B slot (tid&7)^(row&7)
  const int sr = tid >> 3;                        // 0..63
  const int ks8 = ((tid & 7) ^ (sr & 7)) << 3;    // element offset in 64-wide row
  const bf16* Ag = A + (size_t)(m0 + sr) * lda + ks8;
  const bf16* Bg = Bm + (size_t)(n0 + sr) * ldb + ks8;

  // read-side swizzle: slot (kk*4+quad) ^ (row&7); row&7 == l15&7 for all frags
  const int swz0 = ((quad) ^ (l15 & 7)) << 3;
  const int swz1 = ((4 + quad) ^ (l15 & 7)) << 3;

  f32x4 acc[8][4];
#pragma unroll
  for (int i = 0; i < 8; ++i)
#pragma unroll
    for (int j = 0; j < 4; ++j)
#pragma unroll
      for (int r = 0; r < 4; ++r) acc[i][j][r] = 0.f;

  const int NT = K >> 6;

  // stage half-tile H (rows H*128..H*128+127) of K-tile TK into ARR
#define STG_A(ARR, H, TK)                                                     \
  do {                                                                        \
    _Pragma("unroll") for (int j_ = 0; j_ < 2; ++j_) {                        \
      const int c_ = (H) * 2 + j_;                                            \
      stage16(Ag + (size_t)(c_ * 64) * lda + (size_t)(TK) * 64,               \
              &ARR[(c_ * 64 + wid * 8) * 64]);                                \
    }                                                                         \
  } while (0)
#define STG_B(ARR, H, TK)                                                     \
  do {                                                                        \
    _Pragma("unroll") for (int j_ = 0; j_ < 2; ++j_) {                        \
      const int c_ = (H) * 2 + j_;                                            \
      stage16(Bg + (size_t)(c_ * 64) * ldb + (size_t)(TK) * 64,               \
              &ARR[(c_ * 64 + wid * 8) * 64]);                                \
    }                                                                         \
  } while (0)

  // ping-pong fragment registers
  bf16x8 aq0[4][2], aq1[4][2], b0[2][2], b1[2][2];

#define RDA(DST, MH, ARR)                                                     \
  do {                                                                        \
    _Pragma("unroll") for (int mi_ = 0; mi_ < 4; ++mi_) {                     \
      const int arow_ = wr * 128 + (MH) * 64 + mi_ * 16 + l15;                \
      DST[mi_][0] = *(const bf16x8*)(&ARR[arow_ * 64] + swz0);                \
      DST[mi_][1] = *(const bf16x8*)(&ARR[arow_ * 64] + swz1);                \
    }                                                                         \
  } while (0)
#define RDB(DST, NH, ARR)                                                     \
  do {                                                                        \
    _Pragma("unroll") for (int ni_ = 0; ni_ < 2; ++ni_) {                     \
      const int brow_ = wc * 64 + (NH) * 32 + ni_ * 16 + l15;                 \
      DST[ni_][0] = *(const bf16x8*)(&ARR[brow_ * 64] + swz0);                \
      DST[ni_][1] = *(const bf16x8*)(&ARR[brow_ * 64] + swz1);                \
    }                                                                         \
  } while (0)
#define MFMAQ(MH, NH, AA, BB)                                                 \
  do {                                                                        \
    __builtin_amdgcn_s_setprio(1);                                            \
    _Pragma("unroll") for (int mi_ = 0; mi_ < 4; ++mi_)                       \
        _Pragma("unroll") for (int ni_ = 0; ni_ < 2; ++ni_) {                 \
      acc[(MH)*4 + mi_][(NH)*2 + ni_] = __builtin_amdgcn_mfma_f32_16x16x32_bf16( \
          AA[mi_][0], BB[ni_][0], acc[(MH)*4 + mi_][(NH)*2 + ni_], 0, 0, 0);  \
      acc[(MH)*4 + mi_][(NH)*2 + ni_] = __builtin_amdgcn_mfma_f32_16x16x32_bf16( \
          AA[mi_][1], BB[ni_][1], acc[(MH)*4 + mi_][(NH)*2 + ni_], 0, 0, 0);  \
    }                                                                         \
    __builtin_amdgcn_s_setprio(0);                                            \
  } while (0)

  // one K-tile, compile-time buffer bindings (SELF = tile parity, OTH = next)
#define TILE(SAs, SBs, SAo, SBo, T)                                           \
  do {                                                                        \
    const int tn_ = ((T) + 1 < NT) ? (T) + 1 : NT - 1;                        \
    const int tnn_ = ((T) + 2 < NT) ? (T) + 2 : NT - 1;                       \
    /* ph1 */                                                                 \
    WAITVM(4);                                                                \
    SCHB();                                                                   \
    STG_B(SBo, 1, tn_);                                                       \
    RDB(b1, 1, SBs);                                                          \
    MFMAQ(0, 0, aq0, b0);                                                     \
    BARX();                                                                   \
    /* ph2 */                                                                 \
    STG_A(SAo, 1, tn_);                                                       \
    RDA(aq1, 1, SAs);                                                         \
    MFMAQ(0, 1, aq0, b1);                                                     \
    BARX();                                                                   \
    /* ph3 */                                                                 \
    STG_B(SBs, 0, tnn_);                                                      \
    MFMAQ(1, 0, aq1, b0);                                                     \
    BARX();                                                                   \
    /* ph4 */                                                                 \
    WAITVM(6);                                                                \
    SCHB();                                                                   \
    STG_A(SAs, 0, tnn_);                                                      \
    RDA(aq0, 0, SAo);                                                         \
    RDB(b0, 0, SBo);                                                          \
    MFMAQ(1, 1, aq1, b1);                                                     \
    BARX();                                                                   \
  } while (0)

  // prologue: tile0 fully + tile1 khalf0 (12 loads, chronological order)
  STG_B(sB0, 0, 0); STG_A(sA0, 0, 0);
  STG_B(sB0, 1, 0); STG_A(sA0, 1, 0);
  STG_B(sB1, 0, 1); STG_A(sA1, 0, 1);
  WAITVM(8);                          // retire HB0(0), HA0(0)
  SCHB();
  BARX();
  RDA(aq0, 0, sA0);                   // sub0(0)
  RDB(b0, 0, sB0);                    // nh0(0)

  for (int t = 0; t < NT; t += 2) {   // NT even (K%128==0)
    TILE(sA0, sB0, sA1, sB1, t);
    TILE(sA1, sB1, sA0, sB0, t + 1);
  }
  WAITVM(0);                          // drain tail stages (hygiene)

#undef STG_A
#undef STG_B
#undef RDA
#undef RDB
#undef MFMAQ
#undef TILE

  // epilogue: row-major store bursts — 4 consecutive stores per quad-row
  // cover contiguous 128 B (cols wc*64..wc*64+63) -> L2 write-combining.
  float bv[4];
#pragma unroll
  for (int nn = 0; nn < 4; ++nn) bv[nn] = bias[n0 + wc * 64 + nn * 16 + l15];
#pragma unroll
  for (int mm = 0; mm < 8; ++mm) {
#pragma unroll
    for (int r = 0; r < 4; ++r) {
      const int m = m0 + wr * 128 + mm * 16 + quad * 4 + r;
      TO* Crow = C + (size_t)m * ldc + n0 + wc * 64 + l15;
#pragma unroll
      for (int nn = 0; nn < 4; ++nn) {
        float v = acc[mm][nn][r] + bv[nn];
        if (EPI == 1) v = gelu_tanh(v);
        Crow[nn * 16] = (TO)v;
      }
    }
  }
}

// ---------------------------------------------------------------------------
// gate pre-activation GEMM: one gate per block (z = h*2+g), 128x128 tile,
// K = DH = 256. out[m, h*DHD + n] = sum_k xconv[m, h*DHD+k] * W[g][h][n][k]
// ---------------------------------------------------------------------------
__global__ __launch_bounds__(256) void gate_gemm(
    const bf16* __restrict__ xconv,
    const bf16* __restrict__ gxT, const bf16* __restrict__ gaT,
    bf16* __restrict__ gxr, bf16* __restrict__ gar) {
  const int h = blockIdx.z >> 1;
  const int g = blockIdx.z & 1;
  const bf16* A = xconv + h * DHD;                       // lda = DDIM
  const bf16* Bm = (g ? gaT : gxT) + (size_t)h * DHD * DHD;  // ldb = DHD
  bf16* C = (g ? gar : gxr) + h * DHD;                   // ldc = DDIM
  const int n0 = blockIdx.x * 128;
  const int m0 = blockIdx.y * 128;
  __shared__ bf16 As[128 * 32];
  __shared__ bf16 Bs[128 * 32];
  const int tid = threadIdx.x;
  const int lane = tid & 63;
  const int wid = tid >> 6;
  const int waveM = wid >> 1, waveN = wid & 1;
  const int quad = lane >> 4;
  const int l15 = lane & 15;
  const int srow = lane >> 2;
  const int scol = (lane & 3) * 8;

  f32x4 acc[4][4];
#pragma unroll
  for (int i = 0; i < 4; ++i)
#pragma unroll
    for (int j = 0; j < 4; ++j)
#pragma unroll
      for (int r = 0; r < 4; ++r) acc[i][j][r] = 0.f;

  for (int k0 = 0; k0 < DHD; k0 += 32) {
    if (k0) __syncthreads();
#pragma unroll
    for (int cc = 0; cc < 2; ++cc) {
      const int q = wid * 2 + cc;
      const int row = q * 16 + srow;
      stage16(A + (size_t)(m0 + row) * DDIM + k0 + scol, As + q * 512);
      stage16(Bm + (size_t)(n0 + row) * DHD + k0 + scol, Bs + q * 512);
    }
    __syncthreads();
    bf16x8 af[4], bfr[4];
#pragma unroll
    for (int i = 0; i < 4; ++i) {
      af[i]  = *(const bf16x8*)&As[(waveM * 64 + i * 16 + l15) * 32 + quad * 8];
      bfr[i] = *(const bf16x8*)&Bs[(waveN * 64 + i * 16 + l15) * 32 + quad * 8];
    }
#pragma unroll
    for (int i = 0; i < 4; ++i)
#pragma unroll
      for (int j = 0; j < 4; ++j)
        acc[i][j] = __builtin_amdgcn_mfma_f32_16x16x32_bf16(af[i], bfr[j], acc[i][j], 0, 0, 0);
  }

#pragma unroll
  for (int j = 0; j < 4; ++j) {
    const int n = n0 + waveN * 64 + j * 16 + l15;
#pragma unroll
    for (int i = 0; i < 4; ++i) {
#pragma unroll
      for (int r = 0; r < 4; ++r) {
        const int m = m0 + waveM * 64 + i * 16 + quad * 4 + r;
        C[(size_t)m * DDIM + n] = (bf16)acc[i][j][r];
      }
    }
  }
}

// ---------------------------------------------------------------------------
// depthwise causal conv, TW=4; bf16 data, fp32 weights
// ---------------------------------------------------------------------------
__global__ __launch_bounds__(256) void conv_kernel(
    const bf16* __restrict__ xp, const float* __restrict__ cw,
    const float* __restrict__ cb, const int* __restrict__ segp,
    bf16* __restrict__ xc) {
  int v = blockIdx.x * 256 + threadIdx.x;
  int dv = v & (DDIM / 8 - 1);
  int m = v >> 8;
  int d0 = dv * 8;
  int t = m & (TDIM - 1);
  int sp = segp[m];
  float acc[8];
#pragma unroll
  for (int j = 0; j < 8; ++j) acc[j] = cb[d0 + j];
#pragma unroll
  for (int i = 0; i < 4; ++i) {
    int shift = 3 - i;
    if (t >= shift && sp >= shift) {
      bf16x8 xv = *(const bf16x8*)&xp[(size_t)(m - shift) * DDIM + d0];
#pragma unroll
      for (int j = 0; j < 8; ++j) acc[j] = fmaf((float)xv[j], cw[i * DDIM + d0 + j], acc[j]);
    }
  }
  bf16x8 o;
#pragma unroll
  for (int j = 0; j < 8; ++j) o[j] = (bf16)acc[j];
  *(bf16x8*)&xc[(size_t)m * DDIM + d0] = o;
}

// ---------------------------------------------------------------------------
// transpose + convert gate weights: dst[h][j][i] = (bf16)src[h][i][j]
// ---------------------------------------------------------------------------
__global__ __launch_bounds__(256) void transpose_gates(
    const float* __restrict__ gxw, const float* __restrict__ gaw,
    bf16* __restrict__ gxT, bf16* __restrict__ gaT) {
  __shared__ bf16 tile[32][33];
  int zz = blockIdx.z;
  int h = zz >> 1;
  const float* src = (zz & 1) ? gaw : gxw;
  bf16* dst = (zz & 1) ? gaT : gxT;
  int j0 = blockIdx.x * 32;
  int i0 = blockIdx.y * 32;
  int r = threadIdx.x >> 5;
  int c = threadIdx.x & 31;
  for (int rr = r; rr < 32; rr += 8)
    tile[rr][c] = (bf16)src[(size_t)(h * DHD + i0 + rr) * DHD + j0 + c];
  __syncthreads();
  for (int rr = r; rr < 32; rr += 8)
    dst[(size_t)(h * DHD + j0 + rr) * DHD + i0 + c] = tile[c][rr];
}

// ---------------------------------------------------------------------------
// RG-LRU elementwise recompute, shared by scan phases
// ---------------------------------------------------------------------------
__device__ __forceinline__ void lru_elem(float pgx, float pga, float xc,
                                         float spv, bool reset,
                                         float& a, float& nr) {
  const float gx = sigmoid_f(pgx);
  const float ga = sigmoid_f(pga);
  const float la = -8.f * ga * spv;
  a = reset ? 0.f : __expf(la);
  const float mult = reset ? 1.f : sqrtf(fmaxf(1.f - __expf(2.f * la), 0.f));
  nr = xc * gx * mult;
}

// chunked scan phase 1: per (b, chunk, d) compute prod(a) and h across chunk
__global__ __launch_bounds__(256) void scan_phase1(
    const bf16* __restrict__ gxr, const bf16* __restrict__ gar,
    const bf16* __restrict__ xconv,
    const float* __restrict__ gxb, const float* __restrict__ gab,
    const float* __restrict__ apar, const int* __restrict__ segp,
    float* __restrict__ chA, float* __restrict__ chH) {
  int idx = blockIdx.x * 256 + threadIdx.x;
  int d = idx & (DDIM - 1);
  int c = (idx >> 11) & (NCHUNK - 1);
  int b = idx >> 17;
  const float gxbv = gxb[d], gabv = gab[d];
  const float spv = softplus_f(apar[d]);
  const int mrow = b * TDIM + c * LCHUNK;
  size_t base = (size_t)mrow * DDIM + d;
  float A = 1.f, hh = 0.f;
  for (int i = 0; i < LCHUNK; ++i) {
    size_t o = base + (size_t)i * DDIM;
    float a, nr;
    lru_elem((float)gxr[o] + gxbv, (float)gar[o] + gabv, (float)xconv[o],
             spv, segp[mrow + i] == 0, a, nr);
    hh = fmaf(a, hh, nr);
    A *= a;
  }
  int ci = (b * NCHUNK + c) * DDIM + d;
  chA[ci] = A;
  chH[ci] = hh;
}

__global__ __launch_bounds__(256) void scan_phase2(
    const float* __restrict__ chA, const float* __restrict__ chH,
    float* __restrict__ hst) {
  int idx = blockIdx.x * 256 + threadIdx.x;
  int d = idx & (DDIM - 1);
  int b = idx >> 11;
  float s = 0.f;
  for (int c = 0; c < NCHUNK; ++c) {
    int ci = (b * NCHUNK + c) * DDIM + d;
    hst[ci] = s;
    s = fmaf(chA[ci], s, chH[ci]);
  }
}

// phase 3: replay scan with chunk-start state; z = h*y in-place over y
__global__ __launch_bounds__(256) void scan_phase3(
    const bf16* __restrict__ gxr, const bf16* __restrict__ gar,
    const bf16* __restrict__ xconv,
    const float* __restrict__ gxb, const float* __restrict__ gab,
    const float* __restrict__ apar, const int* __restrict__ segp,
    const float* __restrict__ hst, bf16* __restrict__ yz) {
  int idx = blockIdx.x * 256 + threadIdx.x;
  int d = idx & (DDIM - 1);
  int c = (idx >> 11) & (NCHUNK - 1);
  int b = idx >> 17;
  const float gxbv = gxb[d], gabv = gab[d];
  const float spv = softplus_f(apar[d]);
  const int mrow = b * TDIM + c * LCHUNK;
  size_t base = (size_t)mrow * DDIM + d;
  float hh = hst[(b * NCHUNK + c) * DDIM + d];
  for (int i = 0; i < LCHUNK; ++i) {
    size_t o = base + (size_t)i * DDIM;
    float a, nr;
    lru_elem((float)gxr[o] + gxbv, (float)gar[o] + gabv, (float)xconv[o],
             spv, segp[mrow + i] == 0, a, nr);
    hh = fmaf(a, hh, nr);
    yz[o] = (bf16)(hh * (float)yz[o]);
  }
}

// ---------------------------------------------------------------------------
extern "C" void kernel_launch(void* const* d_in, const int* in_sizes, int n_in,
                              void* d_out, int out_size, void* d_ws, size_t ws_size,
                              hipStream_t stream) {
  const float* x    = (const float*)d_in[0];
  const int*   segp = (const int*)d_in[1];
  const float* Wy   = (const float*)d_in[2];
  const float* by   = (const float*)d_in[3];
  const float* Wx   = (const float*)d_in[4];
  const float* bx   = (const float*)d_in[5];
  const float* cw   = (const float*)d_in[6];
  const float* cb   = (const float*)d_in[7];
  const float* gxw  = (const float*)d_in[8];
  const float* gxb  = (const float*)d_in[9];
  const float* gaw  = (const float*)d_in[10];
  const float* gab  = (const float*)d_in[11];
  const float* apar = (const float*)d_in[12];
  const float* Wout = (const float*)d_in[13];
  const float* bout = (const float*)d_in[14];

  const size_t MD = (size_t)MTOT * DDIM;       // 16.78M elements
  const size_t WD = (size_t)DDIM * DDIM;       // 4.19M elements
  // d_out (fp32, 67 MB) as bf16 scratch until the final GEMM:
  bf16* xb    = (bf16*)d_out;                   // lower: xb -> xconv
  bf16* xproj = (bf16*)((char*)d_out + MD * 2); // upper: xproj -> gxr
  bf16* xconv = xb;
  bf16* gxr   = xproj;

  // ws (~92 MB): gar | W1 | WB1 | WB2 | gxT | gaT | chA | chH | hst
  char* ws = (char*)d_ws;
  bf16*  gar = (bf16*)ws;                        // 33.5 MB
  bf16*  W1  = (bf16*)(ws + MD * 2);             // y -> z (33.5 MB)
  bf16*  WB1 = (bf16*)(ws + 2 * MD * 2);         // Wxb, later Woutb (8.4 MB)
  bf16*  WB2 = (bf16*)(ws + 2 * MD * 2 + WD * 2);// Wyb (8.4 MB)
  char*  tail = ws + 2 * MD * 2 + 2 * WD * 2;
  const size_t GW = (size_t)HDIM * DHD * DHD * 2;      // 1 MiB
  const size_t CH = (size_t)BDIM * NCHUNK * DDIM * 4;  // 2 MiB
  bf16*  gxT = (bf16*)tail;
  bf16*  gaT = (bf16*)(tail + GW);
  float* chA = (float*)(tail + 2 * GW);
  float* chH = (float*)(tail + 2 * GW + CH);
  float* hst = (float*)(tail + 2 * GW + 2 * CH);

  dim3 blk(256);
  f2b<<<dim3(MD / 2048), blk, 0, stream>>>(x, xb);
  f2b<<<dim3(WD / 2048), blk, 0, stream>>>(Wx, WB1);
  f2b<<<dim3(WD / 2048), blk, 0, stream>>>(Wy, WB2);
  transpose_gates<<<dim3(8, 8, 16), blk, 0, stream>>>(gxw, gaw, gxT, gaT);

  // xproj = x @ Wx^T + bx ; y = gelu(x @ Wy^T + by)
  gemm256<bf16, 0><<<dim3(8, 32), dim3(512), 0, stream>>>(xb, WB1, bx, xproj, DDIM, DDIM, DDIM, DDIM);
  gemm256<bf16, 1><<<dim3(8, 32), dim3(512), 0, stream>>>(xb, WB2, by, W1, DDIM, DDIM, DDIM, DDIM);

  // xconv in-place over xb (reads xproj; xb dead after the two GEMMs)
  conv_kernel<<<dim3(MTOT * (DDIM / 8) / 256), blk, 0, stream>>>(xproj, cw, cb, segp, xconv);

  // gate pre-activations: gxr over xproj (dead), gar in ws
  gate_gemm<<<dim3(2, 64, 16), blk, 0, stream>>>(xconv, gxT, gaT, gxr, gar);

  // chunked scan with fused RG-LRU elementwise; phase3 writes z = h*y over y
  scan_phase1<<<dim3(BDIM * NCHUNK * DDIM / 256), blk, 0, stream>>>(
      gxr, gar, xconv, gxb, gab, apar, segp, chA, chH);
  scan_phase2<<<dim3(BDIM * DDIM / 256), blk, 0, stream>>>(chA, chH, hst);
  scan_phase3<<<dim3(BDIM * NCHUNK * DDIM / 256), blk, 0, stream>>>(
      gxr, gar, xconv, gxb, gab, apar, segp, hst, W1);

  // out = z @ Wout^T + bout (fp32 over all of d_out; scratch dead)
  f2b<<<dim3(WD / 2048), blk, 0, stream>>>(Wout, WB1);
  gemm256<float, 0><<<dim3(8, 32), dim3(512), 0, stream>>>(W1, WB1, bout, (float*)d_out, DDIM, DDIM, DDIM, DDIM);
}